// Round 12
// baseline (4551.796 us; speedup 1.0000x reference)
//
#include <hip/hip_runtime.h>
#include <cstdint>
#include <cstddef>

#define Hdim 512
#define Tdim 512
#define Bdim 32
#define NWG  256
#define SCAN_THREADS 384

typedef float        f32x4 __attribute__((ext_vector_type(4)));
typedef unsigned int u32x4 __attribute__((ext_vector_type(4)));
typedef unsigned int u32x2 __attribute__((ext_vector_type(2)));

__device__ __forceinline__ float sigmoidf_(float v) {
    return 1.f / (1.f + __expf(-v));
}
__device__ __forceinline__ float tanhf_(float a) {
    float ax = fabsf(a);
    float e  = __expf(-2.f * ax);
    float t  = (1.f - e) / (1.f + e);
    return copysignf(t, a);
}

// ---------------------------------------------------------------------------
// Tag-fused exchange GRU scan (round-11 chassis; changes this round:
//  (1) barrier (d) REMOVED — it sat right after the y/h global stores and
//      __syncthreads' implicit s_waitcnt vmcnt(0) serially drained the HBM
//      store ack (~500-900 cy) into every step. Race-freedom without (d):
//      the gate wave's part4/hlf reads are data-deps of its tag store; any
//      thread reaches next-step hlf/part4 writes only after poll-pass, which
//      requires that tag store; barriers (b)/(c) order everything else.
//  (2) xp prefetch moved AFTER barrier (b) so its loads drain at (c) —
//      hidden under the ~1500-cy dot phase instead of stalling (b).
// Exchange scope: sc1 (agent) — r11-proven; sc0-only is SE scope (broken,
// r4/r6/r10); sc0 sc1 (system) is perf-identical to sc1 (r8 vs r11).
// WG = (bg = wg>>5: 4 batches) x (u = wg&31: 48 W-rows in VGPRs; thread
// (rw,kq) owns 4 rows {rw+12i} x k-slices {4kq+128c}).
// Exchange: uint2 {h_bits, tag=t} per (batch,unit). Consumers poll dwordx4
// until their 8 tags == t; h arrives fused with the tags (1 RT/step).
// Ping-pong: step t reads buf[t&1] (tag t), writes buf[(t+1)&1] (tag t+1).
// ---------------------------------------------------------------------------
__global__ void __launch_bounds__(SCAN_THREADS, 1)
gru_scan(const float* __restrict__ xp,    // [B][Tc][3H]
         const float* __restrict__ Whh,   // [3H][H]
         const float* __restrict__ bhh,   // [3H]
         const int*   __restrict__ lens,  // [B]
         float*       __restrict__ y,     // [B][T][H]
         u32x2*       hb2,                // [2][8][4][512] {h,tag}
         int t0, int Tc)
{
    __shared__ float  hlf[4 * Hdim];     // h, linear, 8 KB
    __shared__ float4 part4[8 * 49];     // dot partials [m][row(48,pad49)]

    const int tid = threadIdx.x;
    const int wg  = blockIdx.x;
    const int u   = wg & 31;
    const int bg  = wg >> 5;
    const int j0  = u << 4;
    const int b0  = bg << 2;
    const int rw  = tid >> 5;        // [0,12)
    const int kq  = tid & 31;        // [0,32)

    // ---- W_hh: 4 rows {rw+12i}, k floats {4kq + 128c .. +3}, registers ----
    float4 w[4][4];
#pragma unroll
    for (int i = 0; i < 4; ++i) {
        int r = rw + 12 * i;
        const float* p = Whh + ((size_t)(((r >> 4) << 9) + j0 + (r & 15)) << 9) + (kq << 2);
#pragma unroll
        for (int c = 0; c < 4; ++c) w[i][c] = *(const float4*)(p + (c << 7));
    }

    const bool isGate = tid < 64;
    const int gjl = tid & 15;
    const int gb  = (tid >> 4) & 3;
    const int jg  = j0 + gjl;
    int   glen = 0;
    float bh_r = 0.f, bh_z = 0.f, bh_n = 0.f;
    const float* xpb = nullptr;
    if (isGate) {
        glen = lens[b0 + gb];
        bh_r = bhh[jg];
        bh_z = bhh[512 + jg];
        bh_n = bhh[1024 + jg];
        xpb = xp + (size_t)(b0 + gb) * Tc * 1536;
    }

    // consumer poll constants (tid < 256): 8 {h,tag} pairs starting at tid*8
    const bool isPoll = tid < 256;
    const int  pb  = tid >> 6;
    const int  pL  = (tid & 63) << 1;
    float* lds_w0 = &hlf[(pb << 9) + (pL << 2)];
    float* lds_w1 = lds_w0 + 4;

    int budget = 1 << 20;   // safety: fail fast instead of hanging

    for (int t = t0; t < t0 + Tc; ++t) {
        const unsigned tg = (unsigned)t;

        // ---- poll buf[t&1] until all 8 tags == t; h arrives with tags ----
        if (isPoll) {
            const u32x2* src = hb2 + ((size_t)(t & 1) << 14) + (bg << 11) + (tid << 3);
            u32x4 q0, q1, q2, q3;
            for (;;) {
                asm volatile(
                    "global_load_dwordx4 %0, %4, off sc1\n\t"
                    "global_load_dwordx4 %1, %4, off offset:16 sc1\n\t"
                    "global_load_dwordx4 %2, %4, off offset:32 sc1\n\t"
                    "global_load_dwordx4 %3, %4, off offset:48 sc1\n\t"
                    "s_waitcnt vmcnt(0)"
                    : "=&v"(q0), "=&v"(q1), "=&v"(q2), "=&v"(q3)
                    : "v"(src) : "memory");
                bool ok = (q0[1] == tg) & (q0[3] == tg) & (q1[1] == tg) & (q1[3] == tg) &
                          (q2[1] == tg) & (q2[3] == tg) & (q3[1] == tg) & (q3[3] == tg);
                if (__all(ok)) break;
                if (--budget < 0) break;
            }
            f32x4 h0 = { __uint_as_float(q0[0]), __uint_as_float(q0[2]),
                         __uint_as_float(q1[0]), __uint_as_float(q1[2]) };
            f32x4 h1 = { __uint_as_float(q2[0]), __uint_as_float(q2[2]),
                         __uint_as_float(q3[0]), __uint_as_float(q3[2]) };
            *(f32x4*)lds_w0 = h0;
            *(f32x4*)lds_w1 = h1;
        }
        __syncthreads();   // (b) h in LDS

        // xp prefetch for THIS step's gate — issued here so the loads drain
        // at barrier (c), hidden under the dot phase.
        float xr = 0.f, xz = 0.f, xn = 0.f;
        if (isGate) {
            const float* xq = xpb + (size_t)(t - t0) * 1536;
            xr = xq[jg];
            xz = xq[512 + jg];
            xn = xq[1024 + jg];
        }

        // ---- dots: 4 rows x 4 batches; h reads consecutive-quad, bank-clean ----
        float acc[4][4];
#pragma unroll
        for (int i = 0; i < 4; ++i)
#pragma unroll
            for (int b = 0; b < 4; ++b) acc[i][b] = 0.f;
#pragma unroll
        for (int b = 0; b < 4; ++b) {
            const float4* hb4 = (const float4*)&hlf[b << 9];
            float4 h0 = hb4[kq];
            float4 h1 = hb4[kq + 32];
            float4 h2 = hb4[kq + 64];
            float4 h3 = hb4[kq + 96];
#pragma unroll
            for (int i = 0; i < 4; ++i) {
                float a = acc[i][b];
                a = fmaf(w[i][0].x, h0.x, a); a = fmaf(w[i][0].y, h0.y, a);
                a = fmaf(w[i][0].z, h0.z, a); a = fmaf(w[i][0].w, h0.w, a);
                a = fmaf(w[i][1].x, h1.x, a); a = fmaf(w[i][1].y, h1.y, a);
                a = fmaf(w[i][1].z, h1.z, a); a = fmaf(w[i][1].w, h1.w, a);
                a = fmaf(w[i][2].x, h2.x, a); a = fmaf(w[i][2].y, h2.y, a);
                a = fmaf(w[i][2].z, h2.z, a); a = fmaf(w[i][2].w, h2.w, a);
                a = fmaf(w[i][3].x, h3.x, a); a = fmaf(w[i][3].y, h3.y, a);
                a = fmaf(w[i][3].z, h3.z, a); a = fmaf(w[i][3].w, h3.w, a);
                acc[i][b] = a;
            }
        }
        // 2-step butterfly over kq bits {0,1}; lanes kq%4==0 hold 64-k partials
#pragma unroll
        for (int mm = 1; mm <= 2; mm <<= 1)
#pragma unroll
            for (int i = 0; i < 4; ++i)
#pragma unroll
                for (int b = 0; b < 4; ++b)
                    acc[i][b] += __shfl_xor(acc[i][b], mm);
        if ((kq & 3) == 0) {
            int mp = kq >> 2;
#pragma unroll
            for (int i = 0; i < 4; ++i)
                part4[mp * 49 + rw + 12 * i] =
                    make_float4(acc[i][0], acc[i][1], acc[i][2], acc[i][3]);
        }
        __syncthreads();   // (c) partials ready (also drains xp loads)

        // ---- gate wave: reduce 8 partials x 3 gates, gate math, fused store ----
        if (isGate) {
            const float* pf = (const float*)part4;
            float s0 = 0.f, s1 = 0.f, s2 = 0.f;
#pragma unroll
            for (int m = 0; m < 8; ++m) {
                int base = ((m * 49 + gjl) << 2) + gb;
                s0 += pf[base];
                s1 += pf[base + 64];    // +16 rows
                s2 += pf[base + 128];   // +32 rows
            }
            float hold = hlf[(gb << 9) + jg];
            float rr = sigmoidf_(xr + s0 + bh_r);
            float zz = sigmoidf_(xz + s1 + bh_z);
            float nn = tanhf_(xn + rr * (s2 + bh_n));
            float hnew = (1.f - zz) * nn + zz * hold;
            bool msk = t < glen;
            float hnext = msk ? hnew : hold;
            y[((size_t)(b0 + gb) * Tdim + t) * Hdim + jg] = msk ? hnew : 0.f;
            u32x2 pv;
            pv[0] = __float_as_uint(hnext);
            pv[1] = (unsigned)(t + 1);
            u32x2* dst = hb2 + ((size_t)((t + 1) & 1) << 14) + (bg << 11) + (gb << 9) + jg;
            asm volatile("global_store_dwordx2 %0, %1, off sc1"
                         :: "v"(dst), "v"(pv) : "memory");
        }
        // barrier (d) removed — see header. Poll-pass at t+1 (which requires
        // this WG's tag store, a data-dep of all step-t LDS reads) plus
        // barriers (b)/(c) provide all needed ordering.
    }
}

// ---------------------------------------------------------------------------
// fp32 NT-GEMM: C[m][n] = sum_k A[row(m)][k]*W[n][k] + bias[n]  (unchanged)
// ---------------------------------------------------------------------------
#define FMA4(c, a, b) { (c).x = fmaf((a), (b).x, (c).x); (c).y = fmaf((a), (b).y, (c).y); \
                        (c).z = fmaf((a), (b).z, (c).z); (c).w = fmaf((a), (b).w, (c).w); }

__global__ void __launch_bounds__(256)
gemm_xproj(const float* __restrict__ A,
           const float* __restrict__ W,     // [1536][512]
           const float* __restrict__ bias,  // [1536]
           float* __restrict__ C,           // [B*Tc][1536]
           int tcLog, int t0)
{
    __shared__ float As[16][132];
    __shared__ float Bs[16][132];
    const int tid = threadIdx.x;
    const int n0  = blockIdx.x << 7;
    const int m0  = blockIdx.y << 7;
    const int tx  = tid & 15;
    const int ty  = tid >> 4;

    const int mrow = tid >> 2;
    const int kcol = (tid & 3) << 2;
    const int Tcm1 = (1 << tcLog) - 1;

    int mg0 = m0 + mrow;
    int mg1 = m0 + 64 + mrow;
    size_t srow0 = (size_t)(mg0 >> tcLog) * Tdim + t0 + (mg0 & Tcm1);
    size_t srow1 = (size_t)(mg1 >> tcLog) * Tdim + t0 + (mg1 & Tcm1);
    const float* Ap0 = A + srow0 * Hdim + kcol;
    const float* Ap1 = A + srow1 * Hdim + kcol;
    const float* Wp0 = W + (size_t)(n0 + mrow) * Hdim + kcol;
    const float* Wp1 = W + (size_t)(n0 + 64 + mrow) * Hdim + kcol;

    float4 c00[4], c01[4], c10[4], c11[4];
#pragma unroll
    for (int i = 0; i < 4; ++i) {
        c00[i] = {0.f,0.f,0.f,0.f}; c01[i] = {0.f,0.f,0.f,0.f};
        c10[i] = {0.f,0.f,0.f,0.f}; c11[i] = {0.f,0.f,0.f,0.f};
    }

    float4 a0 = *(const float4*)(Ap0);
    float4 a1 = *(const float4*)(Ap1);
    float4 b0 = *(const float4*)(Wp0);
    float4 b1 = *(const float4*)(Wp1);

    for (int kt = 0; kt < 512; kt += 16) {
        __syncthreads();
        As[kcol+0][mrow] = a0.x; As[kcol+1][mrow] = a0.y;
        As[kcol+2][mrow] = a0.z; As[kcol+3][mrow] = a0.w;
        As[kcol+0][mrow+64] = a1.x; As[kcol+1][mrow+64] = a1.y;
        As[kcol+2][mrow+64] = a1.z; As[kcol+3][mrow+64] = a1.w;
        Bs[kcol+0][mrow] = b0.x; Bs[kcol+1][mrow] = b0.y;
        Bs[kcol+2][mrow] = b0.z; Bs[kcol+3][mrow] = b0.w;
        Bs[kcol+0][mrow+64] = b1.x; Bs[kcol+1][mrow+64] = b1.y;
        Bs[kcol+2][mrow+64] = b1.z; Bs[kcol+3][mrow+64] = b1.w;
        __syncthreads();
        if (kt + 16 < 512) {
            a0 = *(const float4*)(Ap0 + kt + 16);
            a1 = *(const float4*)(Ap1 + kt + 16);
            b0 = *(const float4*)(Wp0 + kt + 16);
            b1 = *(const float4*)(Wp1 + kt + 16);
        }
#pragma unroll
        for (int kk = 0; kk < 16; ++kk) {
            float4 aA = *(const float4*)&As[kk][ty * 4];
            float4 aB = *(const float4*)&As[kk][64 + ty * 4];
            float4 bA = *(const float4*)&Bs[kk][tx * 4];
            float4 bB = *(const float4*)&Bs[kk][64 + tx * 4];
            FMA4(c00[0], aA.x, bA); FMA4(c01[0], aA.x, bB);
            FMA4(c00[1], aA.y, bA); FMA4(c01[1], aA.y, bB);
            FMA4(c00[2], aA.z, bA); FMA4(c01[2], aA.z, bB);
            FMA4(c00[3], aA.w, bA); FMA4(c01[3], aA.w, bB);
            FMA4(c10[0], aB.x, bA); FMA4(c11[0], aB.x, bB);
            FMA4(c10[1], aB.y, bA); FMA4(c11[1], aB.y, bB);
            FMA4(c10[2], aB.z, bA); FMA4(c11[2], aB.z, bB);
            FMA4(c10[3], aB.w, bA); FMA4(c11[3], aB.w, bB);
        }
    }

    float4 biasA = *(const float4*)(bias + n0 + tx * 4);
    float4 biasB = *(const float4*)(bias + n0 + 64 + tx * 4);
#pragma unroll
    for (int i = 0; i < 4; ++i) {
        size_t row0 = (size_t)m0 + ty * 4 + i;
        size_t row1 = row0 + 64;
        float4 v;
        v.x = c00[i].x + biasA.x; v.y = c00[i].y + biasA.y;
        v.z = c00[i].z + biasA.z; v.w = c00[i].w + biasA.w;
        *(float4*)(C + row0 * 1536 + n0 + tx * 4) = v;
        v.x = c01[i].x + biasB.x; v.y = c01[i].y + biasB.y;
        v.z = c01[i].z + biasB.z; v.w = c01[i].w + biasB.w;
        *(float4*)(C + row0 * 1536 + n0 + 64 + tx * 4) = v;
        v.x = c10[i].x + biasA.x; v.y = c10[i].y + biasA.y;
        v.z = c10[i].z + biasA.z; v.w = c10[i].w + biasA.w;
        *(float4*)(C + row1 * 1536 + n0 + tx * 4) = v;
        v.x = c11[i].x + biasB.x; v.y = c11[i].y + biasB.y;
        v.z = c11[i].z + biasB.z; v.w = c11[i].w + biasB.w;
        *(float4*)(C + row1 * 1536 + n0 + 64 + tx * 4) = v;
    }
}

// ---------------------------------------------------------------------------
extern "C" void kernel_launch(void* const* d_in, const int* in_sizes, int n_in,
                              void* d_out, int out_size, void* d_ws, size_t ws_size,
                              hipStream_t stream) {
    (void)in_sizes; (void)n_in; (void)out_size;
    const float* x    = (const float*)d_in[0];
    const int*   lens = (const int*)d_in[1];
    const float* Wih0 = (const float*)d_in[2];
    const float* Whh0 = (const float*)d_in[3];
    const float* bih0 = (const float*)d_in[4];
    const float* bhh0 = (const float*)d_in[5];
    const float* Wih1 = (const float*)d_in[6];
    const float* Whh1 = (const float*)d_in[7];
    const float* bih1 = (const float*)d_in[8];
    const float* bhh1 = (const float*)d_in[9];
    float* out = (float*)d_out;

    // ws: [xp: B*Tc*1536 f32][hb2_0: 256KB][hb2_1: 256KB]
    const size_t hb2_bytes  = (size_t)2 * 8 * 2048 * 8;   // 2 bufs x 8 grp x 2048 pairs
    const size_t ctrl_bytes = 2 * hb2_bytes;
    int Tc = 512;
    while (Tc > 4 && (size_t)Bdim * Tc * 1536 * 4 + ctrl_bytes > ws_size) Tc >>= 1;
    int tcLog = 31 - __builtin_clz((unsigned)Tc);
    size_t xp_bytes = (size_t)Bdim * Tc * 1536 * 4;

    float* xp = (float*)d_ws;
    char*  ctrl = (char*)d_ws + xp_bytes;
    u32x2* hb2_0 = (u32x2*)ctrl;
    u32x2* hb2_1 = (u32x2*)(ctrl + hb2_bytes);

    (void)hipMemsetAsync(ctrl, 0, ctrl_bytes, stream);

    const int nChunks = Tdim / Tc;
    for (int layer = 0; layer < 2; ++layer) {
        const float* src  = layer ? (const float*)out : x;
        const float* Wih  = layer ? Wih1 : Wih0;
        const float* bih  = layer ? bih1 : bih0;
        const float* Whh  = layer ? Whh1 : Whh0;
        const float* bhhp = layer ? bhh1 : bhh0;
        u32x2* hb2 = layer ? hb2_1 : hb2_0;

        for (int c = 0; c < nChunks; ++c) {
            int t0 = c * Tc;
            dim3 gg(12, (Bdim * Tc) >> 7);
            gemm_xproj<<<gg, dim3(256), 0, stream>>>(src, Wih, bih, xp, tcLog, t0);

            const float* a_xp  = xp;
            const float* a_whh = Whh;
            const float* a_bhh = bhhp;
            const int*   a_ln  = lens;
            float*       a_y   = out;
            u32x2*       a_hb  = hb2;
            int a_t0 = t0;
            int a_tc = Tc;
            void* args[] = { &a_xp, &a_whh, &a_bhh, &a_ln, &a_y, &a_hb, &a_t0, &a_tc };
            (void)hipLaunchCooperativeKernel((const void*)gru_scan, dim3(NWG),
                                             dim3(SCAN_THREADS), args, 0, stream);
        }
    }
}

// Round 13
// 3738.832 us; speedup vs baseline: 1.2174x; 1.2174x over previous
//
#include <hip/hip_runtime.h>
#include <cstdint>
#include <cstddef>

#define Hdim 512
#define Tdim 512
#define Bdim 32
#define NWG  256
#define SCAN_THREADS 384

typedef float        f32x4 __attribute__((ext_vector_type(4)));
typedef unsigned int u32x4 __attribute__((ext_vector_type(4)));
typedef unsigned int u32x2 __attribute__((ext_vector_type(2)));
typedef _Float16     h16x2 __attribute__((ext_vector_type(2)));
typedef _Float16     h16x8 __attribute__((ext_vector_type(8)));

__device__ __forceinline__ float sigmoidf_(float v) {
    return 1.f / (1.f + __expf(-v));
}
__device__ __forceinline__ float tanhf_(float a) {
    float ax = fabsf(a);
    float e  = __expf(-2.f * ax);
    float t  = (1.f - e) / (1.f + e);
    return copysignf(t, a);
}
__device__ __forceinline__ h16x2 pk2(float a, float b) {
    h16x2 r; r[0] = (_Float16)a; r[1] = (_Float16)b; return r;
}

// ---------------------------------------------------------------------------
// PIPELINED two-layer scan: 512 WGs (2/CU). WGs 0-255 = layer 1 (r11 body,
// fp32 W_hh0; publishes h0 ping-pong + y0 8-deep ring). WGs 256-511 = layer 2
// (f16 W_hh1+W_ih1 via fdot2; consumes y0 ring + own h1 ping-pong; writes
// final y). Layer 1 never waits on layer 2 except flow control: overwrite of
// y0 slot t&7 requires layer-2 group progress >= t-6 (wave-4 poll; steady-
// state slack ~5 -> no stall). 513 serial steps replace 1024.
// Scope ledger: sc1 (agent) — r11-proven; sc0-only = SE scope, broken
// (r4/r6/r10); sc0 sc1 perf-identical to sc1 (r8 vs r11). Barrier (d) is
// load-bearing (r12 regression) — kept in both bodies.
// ---------------------------------------------------------------------------
__device__ __forceinline__ void pipe_l1(
    const float* __restrict__ xp, const float* __restrict__ Whh,
    const float* __restrict__ bhh, const int* __restrict__ lens,
    u32x2* h0p, u32x2* y0r, const int* prog, char* smem, int wg)
{
    float*  hlf   = (float*)smem;             // [4][512] f32, 8 KB
    float4* part4 = (float4*)(smem + 8192);   // [8*49]

    const int tid = threadIdx.x;
    const int u   = wg & 31;
    const int bg  = wg >> 5;
    const int j0  = u << 4;
    const int b0  = bg << 2;
    const int rw  = tid >> 5;
    const int kq  = tid & 31;

    float4 w[4][4];
#pragma unroll
    for (int i = 0; i < 4; ++i) {
        int r = rw + 12 * i;
        const float* p = Whh + ((size_t)(((r >> 4) << 9) + j0 + (r & 15)) << 9) + (kq << 2);
#pragma unroll
        for (int c = 0; c < 4; ++c) w[i][c] = *(const float4*)(p + (c << 7));
    }

    const bool isGate = tid < 64;
    const int gjl = tid & 15;
    const int gb  = (tid >> 4) & 3;
    const int jg  = j0 + gjl;
    int   glen = 0;
    float bh_r = 0.f, bh_z = 0.f, bh_n = 0.f;
    const float* xpb = nullptr;
    if (isGate) {
        glen = lens[b0 + gb];
        bh_r = bhh[jg]; bh_z = bhh[512 + jg]; bh_n = bhh[1024 + jg];
        xpb = xp + (size_t)(b0 + gb) * Tdim * 1536;
    }

    const bool isPoll = tid < 256;
    const int  pb  = tid >> 6;
    const int  pL  = (tid & 63) << 1;
    float* lds_w0 = &hlf[(pb << 9) + (pL << 2)];
    float* lds_w1 = lds_w0 + 4;

    float xr = 0.f, xz = 0.f, xn = 0.f;
    if (isGate) { xr = xpb[jg]; xz = xpb[512 + jg]; xn = xpb[1024 + jg]; }

    int budget = 1 << 20;

    for (int t = 0; t < Tdim; ++t) {
        const unsigned tg = (unsigned)t;

        if (isPoll) {
            const u32x2* src = h0p + ((size_t)(t & 1) << 14) + (bg << 11) + (tid << 3);
            u32x4 q0, q1, q2, q3;
            for (;;) {
                asm volatile(
                    "global_load_dwordx4 %0, %4, off sc1\n\t"
                    "global_load_dwordx4 %1, %4, off offset:16 sc1\n\t"
                    "global_load_dwordx4 %2, %4, off offset:32 sc1\n\t"
                    "global_load_dwordx4 %3, %4, off offset:48 sc1\n\t"
                    "s_waitcnt vmcnt(0)"
                    : "=&v"(q0), "=&v"(q1), "=&v"(q2), "=&v"(q3)
                    : "v"(src) : "memory");
                bool ok = (q0[1] == tg) & (q0[3] == tg) & (q1[1] == tg) & (q1[3] == tg) &
                          (q2[1] == tg) & (q2[3] == tg) & (q3[1] == tg) & (q3[3] == tg);
                if (__all(ok)) break;
                if (--budget < 0) break;
            }
            f32x4 h0 = { __uint_as_float(q0[0]), __uint_as_float(q0[2]),
                         __uint_as_float(q1[0]), __uint_as_float(q1[2]) };
            f32x4 h1 = { __uint_as_float(q2[0]), __uint_as_float(q2[2]),
                         __uint_as_float(q3[0]), __uint_as_float(q3[2]) };
            *(f32x4*)lds_w0 = h0;
            *(f32x4*)lds_w1 = h1;
        } else if (tid < 320) {
            // wave 4: flow control — layer-2 group progress >= t-6 before the
            // y0 slot (t&7) overwrite this step (slot last consumed at t-8).
            const int* pp = prog + (bg << 5) + (tid & 31);
            const int need = t - 6;
            for (;;) {
                int pv;
                asm volatile("global_load_dword %0, %1, off sc1\n\t"
                             "s_waitcnt vmcnt(0)"
                             : "=v"(pv) : "v"(pp) : "memory");
                if (__all(pv >= need)) break;
                if (--budget < 0) break;
            }
        }
        float xrn = 0.f, xzn = 0.f, xnn = 0.f;
        if (isGate) {
            int tf = (t + 1 < Tdim) ? t + 1 : t;
            const float* xq = xpb + (size_t)tf * 1536;
            xrn = xq[jg]; xzn = xq[512 + jg]; xnn = xq[1024 + jg];
        }
        __syncthreads();   // (b)

        float acc[4][4];
#pragma unroll
        for (int i = 0; i < 4; ++i)
#pragma unroll
            for (int b = 0; b < 4; ++b) acc[i][b] = 0.f;
#pragma unroll
        for (int b = 0; b < 4; ++b) {
            const float4* hb4 = (const float4*)&hlf[b << 9];
            float4 h0 = hb4[kq];
            float4 h1 = hb4[kq + 32];
            float4 h2 = hb4[kq + 64];
            float4 h3 = hb4[kq + 96];
#pragma unroll
            for (int i = 0; i < 4; ++i) {
                float a = acc[i][b];
                a = fmaf(w[i][0].x, h0.x, a); a = fmaf(w[i][0].y, h0.y, a);
                a = fmaf(w[i][0].z, h0.z, a); a = fmaf(w[i][0].w, h0.w, a);
                a = fmaf(w[i][1].x, h1.x, a); a = fmaf(w[i][1].y, h1.y, a);
                a = fmaf(w[i][1].z, h1.z, a); a = fmaf(w[i][1].w, h1.w, a);
                a = fmaf(w[i][2].x, h2.x, a); a = fmaf(w[i][2].y, h2.y, a);
                a = fmaf(w[i][2].z, h2.z, a); a = fmaf(w[i][2].w, h2.w, a);
                a = fmaf(w[i][3].x, h3.x, a); a = fmaf(w[i][3].y, h3.y, a);
                a = fmaf(w[i][3].z, h3.z, a); a = fmaf(w[i][3].w, h3.w, a);
                acc[i][b] = a;
            }
        }
#pragma unroll
        for (int mm = 1; mm <= 2; mm <<= 1)
#pragma unroll
            for (int i = 0; i < 4; ++i)
#pragma unroll
                for (int b = 0; b < 4; ++b)
                    acc[i][b] += __shfl_xor(acc[i][b], mm);
        if ((kq & 3) == 0) {
            int mp = kq >> 2;
#pragma unroll
            for (int i = 0; i < 4; ++i)
                part4[mp * 49 + rw + 12 * i] =
                    make_float4(acc[i][0], acc[i][1], acc[i][2], acc[i][3]);
        }
        __syncthreads();   // (c)

        if (isGate) {
            const float* pf = (const float*)part4;
            float s0 = 0.f, s1 = 0.f, s2 = 0.f;
#pragma unroll
            for (int m = 0; m < 8; ++m) {
                int base = ((m * 49 + gjl) << 2) + gb;
                s0 += pf[base];
                s1 += pf[base + 64];
                s2 += pf[base + 128];
            }
            float hold = hlf[(gb << 9) + jg];
            float rr = sigmoidf_(xr + s0 + bh_r);
            float zz = sigmoidf_(xz + s1 + bh_z);
            float nn = tanhf_(xn + rr * (s2 + bh_n));
            float hnew = (1.f - zz) * nn + zz * hold;
            bool msk = t < glen;
            float hnext = msk ? hnew : hold;
            float y0v   = msk ? hnew : 0.f;
            u32x2 p0; p0[0] = __float_as_uint(hnext); p0[1] = (unsigned)(t + 1);
            u32x2 p2; p2[0] = __float_as_uint(y0v);   p2[1] = (unsigned)(t + 1);
            u32x2* d0 = h0p + ((size_t)((t + 1) & 1) << 14) + (bg << 11) + (gb << 9) + jg;
            u32x2* d2 = y0r + ((size_t)(t & 7) << 14) + (bg << 11) + (gb << 9) + jg;
            asm volatile("global_store_dwordx2 %0, %1, off sc1"
                         :: "v"(d0), "v"(p0) : "memory");
            asm volatile("global_store_dwordx2 %0, %1, off sc1"
                         :: "v"(d2), "v"(p2) : "memory");
            xr = xrn; xz = xzn; xn = xnn;
        }
        __syncthreads();   // (d) — load-bearing (r12 regression)
    }
}

__device__ __forceinline__ void pipe_l2(
    const float* __restrict__ Whh, const float* __restrict__ bhh,
    const float* __restrict__ Wih, const float* __restrict__ bih,
    const int* __restrict__ lens, float* __restrict__ y,
    u32x2* h1p, u32x2* y0r, int* prog, char* smem, int wg2)
{
    h16x2*  hlH   = (h16x2*)smem;               // [4][256] f16x2 (h1)
    h16x2*  hlY   = hlH + 1024;                 // [4][256] (y0)
    float4* part4 = (float4*)(smem + 8192);     // [16*49]

    const int tid = threadIdx.x;
    const int u   = wg2 & 31;
    const int bg  = wg2 >> 5;
    const int j0  = u << 4;
    const int b0  = bg << 2;
    const int rw  = tid >> 5;
    const int kq  = tid & 31;

    // f16 weights: rows {rw+12i}, k floats {8kq..+7} u {256+8kq..+7}
    h16x2 wh[4][8], wx[4][8];
#pragma unroll
    for (int i = 0; i < 4; ++i) {
        int r = rw + 12 * i;
        size_t grow = (size_t)(((r >> 4) << 9) + j0 + (r & 15)) << 9;
        const float* pa = Whh + grow + (kq << 3);
        const float* pc = Wih + grow + (kq << 3);
#pragma unroll
        for (int c = 0; c < 2; ++c) {
            float4 q0 = *(const float4*)(pa + (c << 8));
            float4 q1 = *(const float4*)(pa + (c << 8) + 4);
            wh[i][4*c+0] = pk2(q0.x, q0.y); wh[i][4*c+1] = pk2(q0.z, q0.w);
            wh[i][4*c+2] = pk2(q1.x, q1.y); wh[i][4*c+3] = pk2(q1.z, q1.w);
            q0 = *(const float4*)(pc + (c << 8));
            q1 = *(const float4*)(pc + (c << 8) + 4);
            wx[i][4*c+0] = pk2(q0.x, q0.y); wx[i][4*c+1] = pk2(q0.z, q0.w);
            wx[i][4*c+2] = pk2(q1.x, q1.y); wx[i][4*c+3] = pk2(q1.z, q1.w);
        }
    }

    const bool isGate = tid < 64;
    const int gjl = tid & 15;
    const int gb  = (tid >> 4) & 3;
    const int jg  = j0 + gjl;
    int   glen = 0;
    float bh_r = 0.f, bh_z = 0.f, bh_n = 0.f, bx_r = 0.f, bx_z = 0.f, bx_n = 0.f;
    float h1reg = 0.f;
    if (isGate) {
        glen = lens[b0 + gb];
        bh_r = bhh[jg]; bh_z = bhh[512 + jg]; bh_n = bhh[1024 + jg];
        bx_r = bih[jg]; bx_z = bih[512 + jg]; bx_n = bih[1024 + jg];
    }

    const bool isPoll = tid < 256;
    const int  pb = tid >> 6;
    const int  u8 = tid & 63;

    int budget = 1 << 20;

    for (int s = 0; s < Tdim; ++s) {
        const unsigned tgY = (unsigned)(s + 1);   // y0 ring tag
        const unsigned tgH = (unsigned)s;         // h1 ping-pong tag

        if (isPoll) {
            const u32x2* sY = y0r + ((size_t)(s & 7) << 14) + (bg << 11) + (tid << 3);
            const u32x2* sH = h1p + ((size_t)(s & 1) << 14) + (bg << 11) + (tid << 3);
            u32x4 a0, a1, a2, a3, c0, c1, c2, c3;
            for (;;) {
                asm volatile(
                    "global_load_dwordx4 %0, %8, off sc1\n\t"
                    "global_load_dwordx4 %1, %8, off offset:16 sc1\n\t"
                    "global_load_dwordx4 %2, %8, off offset:32 sc1\n\t"
                    "global_load_dwordx4 %3, %8, off offset:48 sc1\n\t"
                    "global_load_dwordx4 %4, %9, off sc1\n\t"
                    "global_load_dwordx4 %5, %9, off offset:16 sc1\n\t"
                    "global_load_dwordx4 %6, %9, off offset:32 sc1\n\t"
                    "global_load_dwordx4 %7, %9, off offset:48 sc1\n\t"
                    "s_waitcnt vmcnt(0)"
                    : "=&v"(a0), "=&v"(a1), "=&v"(a2), "=&v"(a3),
                      "=&v"(c0), "=&v"(c1), "=&v"(c2), "=&v"(c3)
                    : "v"(sY), "v"(sH) : "memory");
                bool ok = (a0[1]==tgY)&(a0[3]==tgY)&(a1[1]==tgY)&(a1[3]==tgY)
                        & (a2[1]==tgY)&(a2[3]==tgY)&(a3[1]==tgY)&(a3[3]==tgY)
                        & (c0[1]==tgH)&(c0[3]==tgH)&(c1[1]==tgH)&(c1[3]==tgH)
                        & (c2[1]==tgH)&(c2[3]==tgH)&(c3[1]==tgH)&(c3[3]==tgH);
                if (__all(ok)) break;
                if (--budget < 0) break;
            }
            h16x8 v;
            v[0]=(_Float16)__uint_as_float(a0[0]); v[1]=(_Float16)__uint_as_float(a0[2]);
            v[2]=(_Float16)__uint_as_float(a1[0]); v[3]=(_Float16)__uint_as_float(a1[2]);
            v[4]=(_Float16)__uint_as_float(a2[0]); v[5]=(_Float16)__uint_as_float(a2[2]);
            v[6]=(_Float16)__uint_as_float(a3[0]); v[7]=(_Float16)__uint_as_float(a3[2]);
            ((h16x8*)&hlY[pb << 8])[u8] = v;
            v[0]=(_Float16)__uint_as_float(c0[0]); v[1]=(_Float16)__uint_as_float(c0[2]);
            v[2]=(_Float16)__uint_as_float(c1[0]); v[3]=(_Float16)__uint_as_float(c1[2]);
            v[4]=(_Float16)__uint_as_float(c2[0]); v[5]=(_Float16)__uint_as_float(c2[2]);
            v[6]=(_Float16)__uint_as_float(c3[0]); v[7]=(_Float16)__uint_as_float(c3[2]);
            ((h16x8*)&hlH[pb << 8])[u8] = v;
        }
        __syncthreads();   // (b)

#define MV2(W, SRC, MIDX) do {                                                \
        float acc[4][4] = {};                                                 \
        _Pragma("unroll")                                                     \
        for (int b = 0; b < 4; ++b) {                                         \
            const h16x8* hp = (const h16x8*)&(SRC)[b << 8];                   \
            h16x8 v0 = hp[kq], v1 = hp[kq + 32];                              \
            h16x2 e0={v0[0],v0[1]}, e1={v0[2],v0[3]},                         \
                  e2={v0[4],v0[5]}, e3={v0[6],v0[7]};                         \
            h16x2 f0={v1[0],v1[1]}, f1={v1[2],v1[3]},                         \
                  f2={v1[4],v1[5]}, f3={v1[6],v1[7]};                         \
            _Pragma("unroll")                                                 \
            for (int ii = 0; ii < 4; ++ii) {                                  \
                float a = acc[ii][b];                                         \
                a = __builtin_amdgcn_fdot2(W[ii][0], e0, a, false);           \
                a = __builtin_amdgcn_fdot2(W[ii][1], e1, a, false);           \
                a = __builtin_amdgcn_fdot2(W[ii][2], e2, a, false);           \
                a = __builtin_amdgcn_fdot2(W[ii][3], e3, a, false);           \
                a = __builtin_amdgcn_fdot2(W[ii][4], f0, a, false);           \
                a = __builtin_amdgcn_fdot2(W[ii][5], f1, a, false);           \
                a = __builtin_amdgcn_fdot2(W[ii][6], f2, a, false);           \
                a = __builtin_amdgcn_fdot2(W[ii][7], f3, a, false);           \
                acc[ii][b] = a;                                               \
            }                                                                 \
        }                                                                     \
        _Pragma("unroll")                                                     \
        for (int mm = 1; mm <= 2; mm <<= 1)                                   \
            _Pragma("unroll")                                                 \
            for (int ii = 0; ii < 4; ++ii)                                    \
                _Pragma("unroll")                                             \
                for (int b = 0; b < 4; ++b)                                   \
                    acc[ii][b] += __shfl_xor(acc[ii][b], mm);                 \
        if ((kq & 3) == 0) {                                                  \
            int mp = kq >> 2;                                                 \
            _Pragma("unroll")                                                 \
            for (int ii = 0; ii < 4; ++ii)                                    \
                part4[((MIDX) * 8 + mp) * 49 + rw + 12 * ii] =                \
                    make_float4(acc[ii][0], acc[ii][1], acc[ii][2], acc[ii][3]); \
        }                                                                     \
    } while (0)

        MV2(wh, hlH, 0);
        MV2(wx, hlY, 1);
#undef MV2
        __syncthreads();   // (c)

        if (isGate) {
            const float* pf = (const float*)part4;
            float t0_=0.f, t1_=0.f, t2_=0.f, x0_=0.f, x1_=0.f, x2_=0.f;
#pragma unroll
            for (int m = 0; m < 8; ++m) {
                int b1 = ((m * 49 + gjl) << 2) + gb;
                int b2 = (((8 + m) * 49 + gjl) << 2) + gb;
                t0_ += pf[b1]; t1_ += pf[b1 + 64]; t2_ += pf[b1 + 128];
                x0_ += pf[b2]; x1_ += pf[b2 + 64]; x2_ += pf[b2 + 128];
            }
            float rr = sigmoidf_(x0_ + bx_r + t0_ + bh_r);
            float zz = sigmoidf_(x1_ + bx_z + t1_ + bh_z);
            float nn = tanhf_(x2_ + bx_n + rr * (t2_ + bh_n));
            float hnew = (1.f - zz) * nn + zz * h1reg;
            bool msk = s < glen;
            h1reg = msk ? hnew : h1reg;
            y[((size_t)(b0 + gb) * Tdim + s) * Hdim + jg] = msk ? hnew : 0.f;
            u32x2 pv; pv[0] = __float_as_uint(h1reg); pv[1] = (unsigned)(s + 1);
            u32x2* dst = h1p + ((size_t)((s + 1) & 1) << 14) + (bg << 11) + (gb << 9) + jg;
            asm volatile("global_store_dwordx2 %0, %1, off sc1"
                         :: "v"(dst), "v"(pv) : "memory");
        }
        if (tid == 0) {
            int pvv = s + 1;
            asm volatile("global_store_dword %0, %1, off sc1"
                         :: "v"(prog + (bg << 5) + u), "v"(pvv) : "memory");
        }
        __syncthreads();   // (d)
    }
}

__global__ void __launch_bounds__(SCAN_THREADS, 3)
gru_pipe(const float* __restrict__ xp,
         const float* __restrict__ Whh0, const float* __restrict__ bhh0,
         const float* __restrict__ Whh1, const float* __restrict__ bhh1,
         const float* __restrict__ Wih1, const float* __restrict__ bih1,
         const int*   __restrict__ lens, float* __restrict__ y,
         u32x2* h0p, u32x2* h1p, u32x2* y0r, int* prog)
{
    __shared__ __align__(16) char smem[21504];
    if (blockIdx.x < 256)
        pipe_l1(xp, Whh0, bhh0, lens, h0p, y0r, prog, smem, blockIdx.x);
    else
        pipe_l2(Whh1, bhh1, Wih1, bih1, lens, y, h1p, y0r, prog, smem,
                blockIdx.x - 256);
}

// ---------------------------------------------------------------------------
// Round-11 single-layer scan — fallback when the 512-WG pipe can't co-reside.
// ---------------------------------------------------------------------------
__global__ void __launch_bounds__(SCAN_THREADS, 1)
gru_scan(const float* __restrict__ xp, const float* __restrict__ Whh,
         const float* __restrict__ bhh, const int* __restrict__ lens,
         float* __restrict__ y, u32x2* hb2, int t0, int Tc)
{
    __shared__ float  hlf[4 * Hdim];
    __shared__ float4 part4[8 * 49];

    const int tid = threadIdx.x;
    const int wg  = blockIdx.x;
    const int u   = wg & 31;
    const int bg  = wg >> 5;
    const int j0  = u << 4;
    const int b0  = bg << 2;
    const int rw  = tid >> 5;
    const int kq  = tid & 31;

    float4 w[4][4];
#pragma unroll
    for (int i = 0; i < 4; ++i) {
        int r = rw + 12 * i;
        const float* p = Whh + ((size_t)(((r >> 4) << 9) + j0 + (r & 15)) << 9) + (kq << 2);
#pragma unroll
        for (int c = 0; c < 4; ++c) w[i][c] = *(const float4*)(p + (c << 7));
    }

    const bool isGate = tid < 64;
    const int gjl = tid & 15;
    const int gb  = (tid >> 4) & 3;
    const int jg  = j0 + gjl;
    int   glen = 0;
    float bh_r = 0.f, bh_z = 0.f, bh_n = 0.f;
    const float* xpb = nullptr;
    if (isGate) {
        glen = lens[b0 + gb];
        bh_r = bhh[jg]; bh_z = bhh[512 + jg]; bh_n = bhh[1024 + jg];
        xpb = xp + (size_t)(b0 + gb) * Tc * 1536;
    }

    const bool isPoll = tid < 256;
    const int  pb  = tid >> 6;
    const int  pL  = (tid & 63) << 1;
    float* lds_w0 = &hlf[(pb << 9) + (pL << 2)];
    float* lds_w1 = lds_w0 + 4;

    float xr = 0.f, xz = 0.f, xn = 0.f;
    if (isGate) { xr = xpb[jg]; xz = xpb[512 + jg]; xn = xpb[1024 + jg]; }

    int budget = 1 << 20;

    for (int t = t0; t < t0 + Tc; ++t) {
        const unsigned tg = (unsigned)t;
        if (isPoll) {
            const u32x2* src = hb2 + ((size_t)(t & 1) << 14) + (bg << 11) + (tid << 3);
            u32x4 q0, q1, q2, q3;
            for (;;) {
                asm volatile(
                    "global_load_dwordx4 %0, %4, off sc1\n\t"
                    "global_load_dwordx4 %1, %4, off offset:16 sc1\n\t"
                    "global_load_dwordx4 %2, %4, off offset:32 sc1\n\t"
                    "global_load_dwordx4 %3, %4, off offset:48 sc1\n\t"
                    "s_waitcnt vmcnt(0)"
                    : "=&v"(q0), "=&v"(q1), "=&v"(q2), "=&v"(q3)
                    : "v"(src) : "memory");
                bool ok = (q0[1] == tg) & (q0[3] == tg) & (q1[1] == tg) & (q1[3] == tg) &
                          (q2[1] == tg) & (q2[3] == tg) & (q3[1] == tg) & (q3[3] == tg);
                if (__all(ok)) break;
                if (--budget < 0) break;
            }
            f32x4 h0 = { __uint_as_float(q0[0]), __uint_as_float(q0[2]),
                         __uint_as_float(q1[0]), __uint_as_float(q1[2]) };
            f32x4 h1 = { __uint_as_float(q2[0]), __uint_as_float(q2[2]),
                         __uint_as_float(q3[0]), __uint_as_float(q3[2]) };
            *(f32x4*)lds_w0 = h0;
            *(f32x4*)lds_w1 = h1;
        }
        float xrn = 0.f, xzn = 0.f, xnn = 0.f;
        if (isGate) {
            int tf = (t + 1 < t0 + Tc) ? (t + 1 - t0) : (t - t0);
            const float* xq = xpb + (size_t)tf * 1536;
            xrn = xq[jg]; xzn = xq[512 + jg]; xnn = xq[1024 + jg];
        }
        __syncthreads();

        float acc[4][4];
#pragma unroll
        for (int i = 0; i < 4; ++i)
#pragma unroll
            for (int b = 0; b < 4; ++b) acc[i][b] = 0.f;
#pragma unroll
        for (int b = 0; b < 4; ++b) {
            const float4* hb4 = (const float4*)&hlf[b << 9];
            float4 h0 = hb4[kq];
            float4 h1 = hb4[kq + 32];
            float4 h2 = hb4[kq + 64];
            float4 h3 = hb4[kq + 96];
#pragma unroll
            for (int i = 0; i < 4; ++i) {
                float a = acc[i][b];
                a = fmaf(w[i][0].x, h0.x, a); a = fmaf(w[i][0].y, h0.y, a);
                a = fmaf(w[i][0].z, h0.z, a); a = fmaf(w[i][0].w, h0.w, a);
                a = fmaf(w[i][1].x, h1.x, a); a = fmaf(w[i][1].y, h1.y, a);
                a = fmaf(w[i][1].z, h1.z, a); a = fmaf(w[i][1].w, h1.w, a);
                a = fmaf(w[i][2].x, h2.x, a); a = fmaf(w[i][2].y, h2.y, a);
                a = fmaf(w[i][2].z, h2.z, a); a = fmaf(w[i][2].w, h2.w, a);
                a = fmaf(w[i][3].x, h3.x, a); a = fmaf(w[i][3].y, h3.y, a);
                a = fmaf(w[i][3].z, h3.z, a); a = fmaf(w[i][3].w, h3.w, a);
                acc[i][b] = a;
            }
        }
#pragma unroll
        for (int mm = 1; mm <= 2; mm <<= 1)
#pragma unroll
            for (int i = 0; i < 4; ++i)
#pragma unroll
                for (int b = 0; b < 4; ++b)
                    acc[i][b] += __shfl_xor(acc[i][b], mm);
        if ((kq & 3) == 0) {
            int mp = kq >> 2;
#pragma unroll
            for (int i = 0; i < 4; ++i)
                part4[mp * 49 + rw + 12 * i] =
                    make_float4(acc[i][0], acc[i][1], acc[i][2], acc[i][3]);
        }
        __syncthreads();

        if (isGate) {
            const float* pf = (const float*)part4;
            float s0 = 0.f, s1 = 0.f, s2 = 0.f;
#pragma unroll
            for (int m = 0; m < 8; ++m) {
                int base = ((m * 49 + gjl) << 2) + gb;
                s0 += pf[base];
                s1 += pf[base + 64];
                s2 += pf[base + 128];
            }
            float hold = hlf[(gb << 9) + jg];
            float rr = sigmoidf_(xr + s0 + bh_r);
            float zz = sigmoidf_(xz + s1 + bh_z);
            float nn = tanhf_(xn + rr * (s2 + bh_n));
            float hnew = (1.f - zz) * nn + zz * hold;
            bool msk = t < glen;
            float hnext = msk ? hnew : hold;
            y[((size_t)(b0 + gb) * Tdim + t) * Hdim + jg] = msk ? hnew : 0.f;
            u32x2 pv;
            pv[0] = __float_as_uint(hnext);
            pv[1] = (unsigned)(t + 1);
            u32x2* dst = hb2 + ((size_t)((t + 1) & 1) << 14) + (bg << 11) + (gb << 9) + jg;
            asm volatile("global_store_dwordx2 %0, %1, off sc1"
                         :: "v"(dst), "v"(pv) : "memory");
            xr = xrn; xz = xzn; xn = xnn;
        }
        __syncthreads();
    }
}

// ---------------------------------------------------------------------------
// fp32 NT-GEMM (unchanged)
// ---------------------------------------------------------------------------
#define FMA4(c, a, b) { (c).x = fmaf((a), (b).x, (c).x); (c).y = fmaf((a), (b).y, (c).y); \
                        (c).z = fmaf((a), (b).z, (c).z); (c).w = fmaf((a), (b).w, (c).w); }

__global__ void __launch_bounds__(256)
gemm_xproj(const float* __restrict__ A,
           const float* __restrict__ W,
           const float* __restrict__ bias,
           float* __restrict__ C,
           int tcLog, int t0)
{
    __shared__ float As[16][132];
    __shared__ float Bs[16][132];
    const int tid = threadIdx.x;
    const int n0  = blockIdx.x << 7;
    const int m0  = blockIdx.y << 7;
    const int tx  = tid & 15;
    const int ty  = tid >> 4;

    const int mrow = tid >> 2;
    const int kcol = (tid & 3) << 2;
    const int Tcm1 = (1 << tcLog) - 1;

    int mg0 = m0 + mrow;
    int mg1 = m0 + 64 + mrow;
    size_t srow0 = (size_t)(mg0 >> tcLog) * Tdim + t0 + (mg0 & Tcm1);
    size_t srow1 = (size_t)(mg1 >> tcLog) * Tdim + t0 + (mg1 & Tcm1);
    const float* Ap0 = A + srow0 * Hdim + kcol;
    const float* Ap1 = A + srow1 * Hdim + kcol;
    const float* Wp0 = W + (size_t)(n0 + mrow) * Hdim + kcol;
    const float* Wp1 = W + (size_t)(n0 + 64 + mrow) * Hdim + kcol;

    float4 c00[4], c01[4], c10[4], c11[4];
#pragma unroll
    for (int i = 0; i < 4; ++i) {
        c00[i] = {0.f,0.f,0.f,0.f}; c01[i] = {0.f,0.f,0.f,0.f};
        c10[i] = {0.f,0.f,0.f,0.f}; c11[i] = {0.f,0.f,0.f,0.f};
    }

    float4 a0 = *(const float4*)(Ap0);
    float4 a1 = *(const float4*)(Ap1);
    float4 b0 = *(const float4*)(Wp0);
    float4 b1 = *(const float4*)(Wp1);

    for (int kt = 0; kt < 512; kt += 16) {
        __syncthreads();
        As[kcol+0][mrow] = a0.x; As[kcol+1][mrow] = a0.y;
        As[kcol+2][mrow] = a0.z; As[kcol+3][mrow] = a0.w;
        As[kcol+0][mrow+64] = a1.x; As[kcol+1][mrow+64] = a1.y;
        As[kcol+2][mrow+64] = a1.z; As[kcol+3][mrow+64] = a1.w;
        Bs[kcol+0][mrow] = b0.x; Bs[kcol+1][mrow] = b0.y;
        Bs[kcol+2][mrow] = b0.z; Bs[kcol+3][mrow] = b0.w;
        Bs[kcol+0][mrow+64] = b1.x; Bs[kcol+1][mrow+64] = b1.y;
        Bs[kcol+2][mrow+64] = b1.z; Bs[kcol+3][mrow+64] = b1.w;
        __syncthreads();
        if (kt + 16 < 512) {
            a0 = *(const float4*)(Ap0 + kt + 16);
            a1 = *(const float4*)(Ap1 + kt + 16);
            b0 = *(const float4*)(Wp0 + kt + 16);
            b1 = *(const float4*)(Wp1 + kt + 16);
        }
#pragma unroll
        for (int kk = 0; kk < 16; ++kk) {
            float4 aA = *(const float4*)&As[kk][ty * 4];
            float4 aB = *(const float4*)&As[kk][64 + ty * 4];
            float4 bA = *(const float4*)&Bs[kk][tx * 4];
            float4 bB = *(const float4*)&Bs[kk][64 + tx * 4];
            FMA4(c00[0], aA.x, bA); FMA4(c01[0], aA.x, bB);
            FMA4(c00[1], aA.y, bA); FMA4(c01[1], aA.y, bB);
            FMA4(c00[2], aA.z, bA); FMA4(c01[2], aA.z, bB);
            FMA4(c00[3], aA.w, bA); FMA4(c01[3], aA.w, bB);
            FMA4(c10[0], aB.x, bA); FMA4(c11[0], aB.x, bB);
            FMA4(c10[1], aB.y, bA); FMA4(c11[1], aB.y, bB);
            FMA4(c10[2], aB.z, bA); FMA4(c11[2], aB.z, bB);
            FMA4(c10[3], aB.w, bA); FMA4(c11[3], aB.w, bB);
        }
    }

    float4 biasA = *(const float4*)(bias + n0 + tx * 4);
    float4 biasB = *(const float4*)(bias + n0 + 64 + tx * 4);
#pragma unroll
    for (int i = 0; i < 4; ++i) {
        size_t row0 = (size_t)m0 + ty * 4 + i;
        size_t row1 = row0 + 64;
        float4 v;
        v.x = c00[i].x + biasA.x; v.y = c00[i].y + biasA.y;
        v.z = c00[i].z + biasA.z; v.w = c00[i].w + biasA.w;
        *(float4*)(C + row0 * 1536 + n0 + tx * 4) = v;
        v.x = c01[i].x + biasB.x; v.y = c01[i].y + biasB.y;
        v.z = c01[i].z + biasB.z; v.w = c01[i].w + biasB.w;
        *(float4*)(C + row0 * 1536 + n0 + 64 + tx * 4) = v;
        v.x = c10[i].x + biasA.x; v.y = c10[i].y + biasA.y;
        v.z = c10[i].z + biasA.z; v.w = c10[i].w + biasA.w;
        *(float4*)(C + row1 * 1536 + n0 + tx * 4) = v;
        v.x = c11[i].x + biasB.x; v.y = c11[i].y + biasB.y;
        v.z = c11[i].z + biasB.z; v.w = c11[i].w + biasB.w;
        *(float4*)(C + row1 * 1536 + n0 + 64 + tx * 4) = v;
    }
}

// ---------------------------------------------------------------------------
extern "C" void kernel_launch(void* const* d_in, const int* in_sizes, int n_in,
                              void* d_out, int out_size, void* d_ws, size_t ws_size,
                              hipStream_t stream) {
    (void)in_sizes; (void)n_in; (void)out_size;
    const float* x    = (const float*)d_in[0];
    const int*   lens = (const int*)d_in[1];
    const float* Wih0 = (const float*)d_in[2];
    const float* Whh0 = (const float*)d_in[3];
    const float* bih0 = (const float*)d_in[4];
    const float* bhh0 = (const float*)d_in[5];
    const float* Wih1 = (const float*)d_in[6];
    const float* Whh1 = (const float*)d_in[7];
    const float* bih1 = (const float*)d_in[8];
    const float* bhh1 = (const float*)d_in[9];
    float* out = (float*)d_out;

    // ws: [xp][h0p 256KB][h1p 256KB][y0r 1MB][prog 1KB]
    const size_t h_bytes   = (size_t)2 * 8 * 2048 * 8;     // per ping-pong set
    const size_t y0_bytes  = (size_t)8 * 8 * 2048 * 8;     // 8-deep ring
    const size_t ctrl_bytes = 2 * h_bytes + y0_bytes + 1024;
    int Tc = 512;
    while (Tc > 4 && (size_t)Bdim * Tc * 1536 * 4 + ctrl_bytes > ws_size) Tc >>= 1;
    int tcLog = 31 - __builtin_clz((unsigned)Tc);
    size_t xp_bytes = (size_t)Bdim * Tc * 1536 * 4;

    float* xp = (float*)d_ws;
    char*  ctrl = (char*)d_ws + xp_bytes;
    u32x2* h0p = (u32x2*)ctrl;
    u32x2* h1p = (u32x2*)(ctrl + h_bytes);
    u32x2* y0r = (u32x2*)(ctrl + 2 * h_bytes);
    int*   prog = (int*)(ctrl + 2 * h_bytes + y0_bytes);

    (void)hipMemsetAsync(ctrl, 0, ctrl_bytes, stream);

    int maxB = 0;
    (void)hipOccupancyMaxActiveBlocksPerMultiprocessor(&maxB, (const void*)gru_pipe,
                                                       SCAN_THREADS, 0);

    if (Tc == 512 && maxB >= 2) {
        dim3 gg(12, (Bdim * 512) >> 7);
        gemm_xproj<<<gg, dim3(256), 0, stream>>>(x, Wih0, bih0, xp, 9, 0);
        const float* a_xp = xp;
        const float* a_w0 = Whh0;  const float* a_b0 = bhh0;
        const float* a_w1 = Whh1;  const float* a_b1 = bhh1;
        const float* a_wx = Wih1;  const float* a_bx = bih1;
        const int*   a_ln = lens;
        float*       a_y  = out;
        u32x2* a_h0 = h0p; u32x2* a_h1 = h1p; u32x2* a_y0 = y0r;
        int*   a_pg = prog;
        void* args[] = { &a_xp, &a_w0, &a_b0, &a_w1, &a_b1, &a_wx, &a_bx,
                         &a_ln, &a_y, &a_h0, &a_h1, &a_y0, &a_pg };
        (void)hipLaunchCooperativeKernel((const void*)gru_pipe, dim3(2 * NWG),
                                         dim3(SCAN_THREADS), args, 0, stream);
    } else {
        const int nChunks = Tdim / Tc;
        for (int layer = 0; layer < 2; ++layer) {
            const float* src  = layer ? (const float*)out : x;
            const float* Wih  = layer ? Wih1 : Wih0;
            const float* bih  = layer ? bih1 : bih0;
            const float* Whh  = layer ? Whh1 : Whh0;
            const float* bhhp = layer ? bhh1 : bhh0;
            u32x2* hb2 = layer ? h1p : h0p;
            for (int c = 0; c < nChunks; ++c) {
                int t0 = c * Tc;
                dim3 gg(12, (Bdim * Tc) >> 7);
                gemm_xproj<<<gg, dim3(256), 0, stream>>>(src, Wih, bih, xp, tcLog, t0);
                const float* a_xp  = xp;
                const float* a_whh = Whh;
                const float* a_bhh = bhhp;
                const int*   a_ln  = lens;
                float*       a_y   = out;
                u32x2*       a_hb  = hb2;
                int a_t0 = t0;
                int a_tc = Tc;
                void* args[] = { &a_xp, &a_whh, &a_bhh, &a_ln, &a_y, &a_hb, &a_t0, &a_tc };
                (void)hipLaunchCooperativeKernel((const void*)gru_scan, dim3(NWG),
                                                 dim3(SCAN_THREADS), args, 0, stream);
            }
        }
    }
}